// Round 11
// baseline (105.678 us; speedup 1.0000x reference)
//
#include <hip/hip_runtime.h>

// WeightedTensorProduct: out[b, seg[k], c] += x1[b,M1[k],c]*x2[b,M2[k],c]*CG[k]*W[l_ind[k],c]
// Structure is a deterministic function of L=3 -> replicated at compile time.
// R6 (kept): compute core = readlane-cg + LDS-w + unrolled (mo,pair) loops.
// R11: HBM access granularity. Ledger invariant: every variant streams at
//      ~2.2TB/s effective (R3 2.3, R8 2.0, R7's regression exactly tracks its
//      fetch increase), while harness fills (dwordx4) hit 6.1TB/s. All our x
//      reads were single-dword. Fix: block covers 2 batches; x1/x2 rows
//      fetched as float4 and bounced through ONE shared 16KB LDS buffer in
//      two phases (loads all issued upfront; LDS total 33.8KB -> 4 blocks/CU).
//      Stores remain dword this round (isolate the read-side variable).

#define LMAX 3
#define MOUT 16          // (L+1)^2
#define CCH 128          // channels
#define NTRI 34
#define NNZ 478
#define NPAIR 156        // nonempty (output-order, triple) pairs
#define NCGV 8           // ceil(NNZ/64) VGPRs holding cg per wave
#define BROW (MOUT * CCH)   // 2048 floats per batch row-block

struct Tables {
    int n_tri = 0;
    int nnz = 0;
    int np = 0;
    int tl[NTRI] = {}, tl1[NTRI] = {}, tl2[NTRI] = {};
    int M1[NNZ] = {}, M2[NNZ] = {};
    int pair_tri[NPAIR] = {};
    int pair_kstart[NPAIR + 1] = {};
    int mo_pstart[MOUT + 1] = {};
};

constexpr Tables build_tables() {
    Tables T{};
    // triples, insertion order == tri_index order in the reference
    for (int l1 = 0; l1 <= LMAX; ++l1) {
        for (int l2 = 0; l2 <= LMAX; ++l2) {
            int lo = l1 - l2; if (lo < 0) lo = -lo;
            int hi = l1 + l2; if (hi > LMAX) hi = LMAX;
            for (int l = lo; l <= hi; ++l) {
                T.tl[T.n_tri] = l; T.tl1[T.n_tri] = l1; T.tl2[T.n_tri] = l2;
                ++T.n_tri;
            }
        }
    }
    // rows sorted by output order Mo; entries grouped by (Mo, triple)
    for (int l = 0; l <= LMAX; ++l) {
        for (int m = -l; m <= l; ++m) {
            const int Mo = l * l + l + m;
            T.mo_pstart[Mo] = T.np;
            for (int t = 0; t < T.n_tri; ++t) {
                if (T.tl[t] != l) continue;
                const int l1 = T.tl1[t], l2 = T.tl2[t];
                int lo = (-l1 > m - l2) ? -l1 : m - l2;
                int hi = (l1 < m + l2) ? l1 : m + l2;
                if (lo > hi) continue;
                T.pair_tri[T.np] = t;
                T.pair_kstart[T.np] = T.nnz;
                ++T.np;
                for (int m1 = lo; m1 <= hi; ++m1) {
                    const int m2 = m - m1;
                    T.M1[T.nnz] = l1 * l1 + l1 + m1;
                    T.M2[T.nnz] = l2 * l2 + l2 + m2;
                    ++T.nnz;
                }
            }
        }
    }
    T.mo_pstart[MOUT] = T.np;
    T.pair_kstart[T.np] = T.nnz;
    return T;
}

constexpr Tables TB = build_tables();
static_assert(TB.nnz == NNZ, "nnz mismatch vs reference _build_structure");
static_assert(TB.n_tri == NTRI, "n_tri mismatch vs reference _build_structure");
static_assert(TB.np == NPAIR, "pair count mismatch");

__global__ __launch_bounds__(256)
void wtp_kernel(const float* __restrict__ x1, const float* __restrict__ x2,
                const float* __restrict__ w, const float* __restrict__ cg,
                float* __restrict__ out, int B) {
    __shared__ float ws[NTRI * CCH];     // 17408 B, per-triple weights
    __shared__ float sxx[2 * BROW];      // 16384 B, x bounce buffer (2 batches)

    const int tid = threadIdx.x + CCH * threadIdx.y;    // 0..255
    const int c = threadIdx.x;                          // channel 0..127
    const int lane = threadIdx.x & 63;                  // lane within wave
    const int yb = threadIdx.y;                         // batch-in-block 0/1
    const int b0 = blockIdx.x * 2;                      // first batch of block

    // ---- issue ALL global loads upfront (float4 granularity for x and w) ----
    // cg staged across the wave's lanes: vcg[j] lane L holds cg[j*64+L].
    float vcg[NCGV];
#pragma unroll
    for (int j = 0; j < NCGV; ++j) {
        const int idx = j * 64 + lane;
        vcg[j] = (idx < NNZ) ? cg[idx] : 0.f;
    }

    // x rows for the block's 2 batches: 2*2048 floats = 1024 float4, contiguous
    const float4* x1v = (const float4*)(x1 + (size_t)b0 * BROW);
    const float4* x2v = (const float4*)(x2 + (size_t)b0 * BROW);
    float4 gx1[4], gx2[4];
#pragma unroll
    for (int j = 0; j < 4; ++j) {
        gx1[j] = x1v[j * 256 + tid];
        gx2[j] = x2v[j * 256 + tid];
    }

    // w: 4352 floats = 1024 float4 + 256-dword tail
    const float4* w4 = (const float4*)w;
    float4* ws4 = (float4*)ws;
#pragma unroll
    for (int j = 0; j < 4; ++j) ws4[j * 256 + tid] = w4[j * 256 + tid];
    if (tid < NTRI * CCH - 4096) ws[4096 + tid] = w[4096 + tid];

    // ---- phase 1: x1 through the bounce buffer ----
    float4* sxx4 = (float4*)sxx;
#pragma unroll
    for (int j = 0; j < 4; ++j) sxx4[j * 256 + tid] = gx1[j];
    __syncthreads();

    float x1r[MOUT];
    const float* sxb = sxx + yb * BROW + c;
#pragma unroll
    for (int m = 0; m < MOUT; ++m) x1r[m] = sxb[m * CCH];
    __syncthreads();

    // ---- phase 2: x2 through the same buffer ----
#pragma unroll
    for (int j = 0; j < 4; ++j) sxx4[j * 256 + tid] = gx2[j];
    __syncthreads();

    float x2r[MOUT];
#pragma unroll
    for (int m = 0; m < MOUT; ++m) x2r[m] = sxb[m * CCH];

    // ---- compute: identical to R6 core ----
    const float* wsc = ws + c;   // ds_read_b32, offset t*512, 2-way bank = free
    float* outb = out + (size_t)(b0 + yb) * BROW + c;
#pragma unroll
    for (int mo = 0; mo < MOUT; ++mo) {
        float acc = 0.f;
#pragma unroll
        for (int p = TB.mo_pstart[mo]; p < TB.mo_pstart[mo + 1]; ++p) {
            float inner = 0.f;
#pragma unroll
            for (int k = TB.pair_kstart[p]; k < TB.pair_kstart[p + 1]; ++k) {
                // wave-uniform cg[k]: v_readlane_b32 (VALU, const lane) -> SGPR
                const float cgk = __int_as_float(
                    __builtin_amdgcn_readlane(__float_as_int(vcg[k >> 6]), k & 63));
                inner = fmaf(cgk, x1r[TB.M1[k]] * x2r[TB.M2[k]], inner);
            }
            acc = fmaf(wsc[TB.pair_tri[p] * CCH], inner, acc);
        }
        outb[(size_t)mo * CCH] = acc;
    }
}

extern "C" void kernel_launch(void* const* d_in, const int* in_sizes, int n_in,
                              void* d_out, int out_size, void* d_ws, size_t ws_size,
                              hipStream_t stream) {
    const float* x1 = (const float*)d_in[0];
    const float* x2 = (const float*)d_in[1];
    const float* w  = (const float*)d_in[2];
    const float* cg = (const float*)d_in[3];
    float* out = (float*)d_out;

    const int B = in_sizes[0] / (MOUT * CCH);   // 2048

    dim3 block(CCH, 2, 1);                      // 256 threads: lane = channel
    dim3 grid(B / 2, 1, 1);                     // block covers 2 batches
    wtp_kernel<<<grid, block, 0, stream>>>(x1, x2, w, cg, out, B);
}